// Round 8
// baseline (147.309 us; speedup 1.0000x reference)
//
#include <hip/hip_runtime.h>
#include <cstdint>

// ---------------- problem constants ----------------
#define H_IN   128
#define W_IN   128
#define C_IN   256
#define O_OUT  256
#define OH     126
#define OW     126

// ---------------- tiling ----------------
#define TY     8                // output tile height
#define TX     8                // output tile width  (64 px = 1 px/lane)
#define IR     (TY + 2)         // 10 input rows staged
#define ICOLS  (TX + 2)         // 10 input cols staged
#define NPIX   (IR * ICOLS)     // 100 staged pixels
#define COLB   516              // bytes per staged pixel (256 bf16 + 2 pad hw)
#define ROWB   5264             // bytes per staged row (pad: word-stride 4 mod 32)
#define IN_BYTES (9 * ROWB + 9 * COLB + COLB)   // 52536 B input region
#define NWAVES 16               // 1024-thread blocks
#define OPW    16               // output channels per wave
#define SSTW   18               // flush words per pixel (16 ch + 2 pad)
#define REGW   1156             // flush words per 16-ch region (64*18=1152 +4; ==4 mod 32)
#define FLUSH_BYTES (16 * REGW * 4)      // 73984 B: all 256 ch in ONE pass
#define LDS_BYTES FLUSH_BYTES            // covers input region (52536); 2 blocks/CU: 147968<=163840

// ---------------- prep: count-sorted grouping + padded entry table ----------
// Channels sorted by nnz count (desc); sorted position p: group g=p>>3, col=p&7.
// Group g padded to S[g]=max count within group (sorted neighbors -> minimal pad).
// Wave w processes groups {w, 31-w} (balanced totals). perm[] lets the conv
// kernel route accumulators back to true output channels during the flush.
__global__ void prep_kernel(const int* __restrict__ wi, const float* __restrict__ wv,
                            int nnz, int* __restrict__ sgS, int* __restrict__ sgBase,
                            int* __restrict__ perm, int2* __restrict__ tab) {
    __shared__ int cnt[256];
    __shared__ int ipos[256];
    __shared__ int prm[256];
    __shared__ int hist[64];
    __shared__ int hbase[65];
    __shared__ int hcur[64];
    __shared__ int smax[32];
    __shared__ int sbase[33];
    __shared__ int is32;
    const int tid = threadIdx.x;
    cnt[tid] = 0;
    if (tid < 64) { hist[tid] = 0; hcur[tid] = 0; }
    if (tid == 0) is32 = 0;
    __syncthreads();
    // dtype detect: int32 layout has nonzero odd words (ih/ic); int64 highs are 0
    int f = 0;
    for (int idx = tid * 2 + 1; idx < nnz * 4; idx += 512) f |= wi[idx];
    if (f) atomicOr(&is32, 1);
    __syncthreads();
    const int stride = is32 ? 4 : 8;
    const int step   = is32 ? 1 : 2;
    for (int e = tid; e < nnz; e += 256)
        atomicAdd(&cnt[wi[e * stride]], 1);
    __syncthreads();
    // counting sort of channels by count, descending (key = 63 - clamped count)
    { int key = 63 - min(cnt[tid], 63); atomicAdd(&hist[key], 1); }
    __syncthreads();
    if (tid == 0) {
        int s = 0;
        for (int i = 0; i < 64; ++i) { hbase[i] = s; s += hist[i]; }
        hbase[64] = s;
    }
    __syncthreads();
    { int key = 63 - min(cnt[tid], 63);
      int pos = hbase[key] + atomicAdd(&hcur[key], 1);
      ipos[tid] = pos; prm[pos] = tid; }
    __syncthreads();
    if (tid < 32) {
        int m = 0;
        for (int k = 0; k < 8; ++k) m = max(m, cnt[prm[tid * 8 + k]]);
        smax[tid] = m;
    }
    __syncthreads();
    if (tid == 0) {
        int s = 0;
        for (int i = 0; i < 32; ++i) { sbase[i] = s; s += 8 * smax[i]; }
        sbase[32] = s;
    }
    __syncthreads();
    const int T = sbase[32];
    for (int i = tid; i < T; i += 256) tab[i] = make_int2(0, 0);  // dummy: lds[A2+0] * 0.0f
    cnt[tid] = 0;            // reuse as per-channel slot cursor
    __syncthreads();
    for (int e = tid; e < nnz; e += 256) {
        int o  = wi[e * stride];
        int h  = wi[e * stride + 1 * step];
        int w_ = wi[e * stride + 2 * step];
        int c  = wi[e * stride + 3 * step];
        // faithful scrambled mapping: flat k in (kh,kw,C), reinterpreted as (C,kh,kw)
        int k   = h * 768 + w_ * 256 + c;
        int cp  = k / 9;
        int rem = k - cp * 9;
        int i_  = rem / 3;
        int j_  = rem - i_ * 3;
        int meta2 = i_ * ROWB + j_ * COLB + cp * 2;   // LDS BYTE delta for tap/channel
        int slot = atomicAdd(&cnt[o], 1);             // duplicates get distinct slots (summed)
        int p    = ipos[o];
        tab[sbase[p >> 3] + slot * 8 + (p & 7)] = make_int2(meta2, __float_as_int(wv[e]));
    }
    if (tid < 32) sgS[tid] = smax[tid];
    if (tid < 33) sgBase[tid] = sbase[tid];
    perm[tid] = prm[tid];
}

// round-to-nearest-even fp32 -> bf16 bits
__device__ inline unsigned short rtne_bf16(float f) {
    unsigned u = __float_as_uint(f);
    u += 0x7FFFu + ((u >> 16) & 1u);
    return (unsigned short)(u >> 16);
}

__device__ __forceinline__ float bfld(const char* b, int off) {
    return __uint_as_float(((unsigned)*(const unsigned short*)(b + off)) << 16);
}

// ---------------- main conv kernel ----------------
// 1024 threads = 16 waves; 2 blocks/CU (LDS 73984*2 <= 160K) -> 32 waves/CU cap.
__global__ __launch_bounds__(1024, 8)
void conv_kernel(const float* __restrict__ in, float* __restrict__ out,
                 const int* __restrict__ sgS, const int* __restrict__ sgBase,
                 const int* __restrict__ perm, const int2* __restrict__ tab) {
    extern __shared__ char smem[];
    float* ldsF = (float*)smem;

    const int tid  = threadIdx.x;
    const int w    = __builtin_amdgcn_readfirstlane(tid >> 6);  // wave id 0..15 in SGPR
    const int lane = tid & 63;
    // XCD-aware bijective swizzle: 1024 blocks = 8 XCDs x 128 contiguous tiles.
    const int flat = ((int)blockIdx.z << 8) | ((int)blockIdx.y << 4) | (int)blockIdx.x;
    const int swz  = ((flat & 7) << 7) | (flat >> 3);
    const int tx = swz & 15, ty = (swz >> 4) & 15, b = swz >> 8;
    const int iy0 = ty * TY, ix0 = tx * TX;
    const float* inb = in + (size_t)b * (H_IN * W_IN * C_IN);

    // ---- early: accumulator -> true-channel map (wave-uniform s_loads, overlap stage) ----
    const int g0 = w, g1 = 31 - w;
    int tcs[OPW];
#pragma unroll
    for (int k = 0; k < OPW; ++k)
        tcs[k] = perm[((k < 8) ? g0 : g1) * 8 + (k & 7)];

    // ---- stage input tile: 100 px x 256 ch fp32 -> bf16 in LDS ----
    for (int base = 0; base < 8; base += 4) {
        float4 v[4];
#pragma unroll
        for (int q = 0; q < 4; ++q) {
            int p = w + (base + q) * NWAVES;
            if (p < NPIX) {
                int r = p / ICOLS, c = p - r * ICOLS;
                int gy = iy0 + r, gx = ix0 + c;
                if (gy < H_IN && gx < W_IN)   // wave-uniform
                    v[q] = *(const float4*)(inb + ((gy * W_IN + gx) << 8) + (lane << 2));
            }
        }
#pragma unroll
        for (int q = 0; q < 4; ++q) {
            int p = w + (base + q) * NWAVES;
            if (p < NPIX) {
                int r = p / ICOLS, c = p - r * ICOLS;
                int gy = iy0 + r, gx = ix0 + c;
                if (gy < H_IN && gx < W_IN) {
                    ushort2 lo, hi;
                    lo.x = rtne_bf16(v[q].x); lo.y = rtne_bf16(v[q].y);
                    hi.x = rtne_bf16(v[q].z); hi.y = rtne_bf16(v[q].w);
                    unsigned short* d = (unsigned short*)(smem + r * ROWB + c * COLB) + (lane << 2);
                    *(ushort2*)(d)     = lo;
                    *(ushort2*)(d + 2) = hi;
                }
            }
        }
    }
    __syncthreads();                                   // (S1) tile staged

    // ---- gather: lane = output pixel (8x8); wave owns sorted groups {w, 31-w} ----
    // R6-proven plain loop (no prefetch: 64-VGPR cap spills any deeper pipeline).
    const int A2  = (lane >> 3) * ROWB + (lane & 7) * COLB;   // byte base of lane's pixel
    const char* basep = (const char*)smem;
    float acc[OPW];
#pragma unroll
    for (int i = 0; i < OPW; ++i) acc[i] = 0.f;

#pragma unroll
    for (int g = 0; g < 2; ++g) {
        const int gi = g ? g1 : g0;
        const int S = sgS[gi];
        const int2* Tg = tab + sgBase[gi];
        for (int slot = 0; slot < S; ++slot) {
            const int4* R = (const int4*)(Tg + (slot << 3));   // 64 B, wave-uniform, cache-hot
            const int4 p0 = R[0];
            const int4 p1 = R[1];
            const int4 p2 = R[2];
            const int4 p3 = R[3];
            acc[g * 8 + 0] += __int_as_float(p0.y) * bfld(basep, A2 + p0.x);
            acc[g * 8 + 1] += __int_as_float(p0.w) * bfld(basep, A2 + p0.z);
            acc[g * 8 + 2] += __int_as_float(p1.y) * bfld(basep, A2 + p1.x);
            acc[g * 8 + 3] += __int_as_float(p1.w) * bfld(basep, A2 + p1.z);
            acc[g * 8 + 4] += __int_as_float(p2.y) * bfld(basep, A2 + p2.x);
            acc[g * 8 + 5] += __int_as_float(p2.w) * bfld(basep, A2 + p2.z);
            acc[g * 8 + 6] += __int_as_float(p3.y) * bfld(basep, A2 + p3.x);
            acc[g * 8 + 7] += __int_as_float(p3.w) * bfld(basep, A2 + p3.z);
        }
    }

    // ---- flush: SINGLE pass through 16-region transpose stage (73984 B) ----
    __syncthreads();                                   // (B1) input region dead
#pragma unroll
    for (int k = 0; k < OPW; ++k) {
        const int tc = tcs[k];
        ldsF[(tc >> 4) * REGW + lane * SSTW + (tc & 15)] = acc[k];
    }
    __syncthreads();                                   // (B2) all channels staged
    {
        const int px = tid >> 4;                       // 0..63
        const int q  = tid & 15;                       // 16-ch region
        const int poy = iy0 + (px >> 3), pox = ix0 + (px & 7);
        if (poy < OH && pox < OW) {
            const float* rb = ldsF + q * REGW + px * SSTW;
            float2 u0 = *(const float2*)(rb + 0);
            float2 u1 = *(const float2*)(rb + 2);
            float2 u2 = *(const float2*)(rb + 4);
            float2 u3 = *(const float2*)(rb + 6);
            float2 u4 = *(const float2*)(rb + 8);
            float2 u5 = *(const float2*)(rb + 10);
            float2 u6 = *(const float2*)(rb + 12);
            float2 u7 = *(const float2*)(rb + 14);
            float* op = out + (((size_t)b * OH + poy) * OW + pox) * O_OUT + q * 16;
            *(float4*)(op + 0)  = make_float4(u0.x, u0.y, u1.x, u1.y);
            *(float4*)(op + 4)  = make_float4(u2.x, u2.y, u3.x, u3.y);
            *(float4*)(op + 8)  = make_float4(u4.x, u4.y, u5.x, u5.y);
            *(float4*)(op + 12) = make_float4(u6.x, u6.y, u7.x, u7.y);
        }
    }
}

// ---------------- host ----------------
extern "C" void kernel_launch(void* const* d_in, const int* in_sizes, int n_in,
                              void* d_out, int out_size, void* d_ws, size_t ws_size,
                              hipStream_t stream) {
    const float* input = (const float*)d_in[0];
    const int*   widx  = (const int*)d_in[1];    // int32 or int64 (runtime-detected)
    const float* wval  = (const float*)d_in[2];
    float* outp = (float*)d_out;
    const int nnz = in_sizes[2];
    const int B = in_sizes[0] / (H_IN * W_IN * C_IN);

    int*  sgS    = (int*)d_ws;                       // 32 ints
    int*  sgBase = sgS + 32;                         // 33 ints
    int*  perm   = (int*)((char*)d_ws + 512);        // 256 ints
    int2* tab    = (int2*)((char*)d_ws + 2048);      // worst case 8*nnz entries

    prep_kernel<<<1, 256, 0, stream>>>(widx, wval, nnz, sgS, sgBase, perm, tab);

    static_assert(LDS_BYTES >= IN_BYTES, "flush region must cover input region");
    static_assert(2 * LDS_BYTES <= 160 * 1024, "need 2 blocks/CU");
    hipFuncSetAttribute((const void*)conv_kernel,
                        hipFuncAttributeMaxDynamicSharedMemorySize, LDS_BYTES);
    dim3 grid((OW + TX - 1) / TX, (OH + TY - 1) / TY, B);
    conv_kernel<<<grid, 1024, LDS_BYTES, stream>>>(input, outp, sgS, sgBase, perm, tab);
}

// Round 9
// 139.991 us; speedup vs baseline: 1.0523x; 1.0523x over previous
//
#include <hip/hip_runtime.h>
#include <cstdint>

// ---------------- problem constants ----------------
#define H_IN   128
#define W_IN   128
#define C_IN   256
#define O_OUT  256
#define OH     126
#define OW     126

// ---------------- tiling ----------------
#define TY     8                // output tile height
#define TX     8                // output tile width  (64 px = 1 px/lane)
#define IR     (TY + 2)         // 10 input rows staged
#define ICOLS  (TX + 2)         // 10 input cols staged
#define NPIX   (IR * ICOLS)     // 100 staged pixels
#define COLB   516              // bytes per staged pixel (256 bf16 + 2 pad hw)
#define ROWB   5264             // bytes per staged row (pad: word-stride 4 mod 32)
#define IN_BYTES (9 * ROWB + 9 * COLB + COLB)   // 52536 B input region
#define NWAVES 16               // 1024-thread blocks
#define OPW    16               // output channels per wave
#define SST    17               // flush words per pixel: ODD -> 17*lane mod 32 bijective
                                //   per half-wave -> conflict-free scalar stores
#define STG_W  (64 * SST)       // 1088 words per region
#define FLUSH_BYTES (8 * STG_W * 4)      // 34816 B <= input region
#define LDS_BYTES IN_BYTES               // 52536; 1024-thr blocks -> 2 blocks/CU cap

// ---------------- prep: count-sorted grouping + padded entry table ----------
// (identical to Round 6 — proven)
__global__ void prep_kernel(const int* __restrict__ wi, const float* __restrict__ wv,
                            int nnz, int* __restrict__ sgS, int* __restrict__ sgBase,
                            int* __restrict__ perm, int2* __restrict__ tab) {
    __shared__ int cnt[256];
    __shared__ int ipos[256];
    __shared__ int prm[256];
    __shared__ int hist[64];
    __shared__ int hbase[65];
    __shared__ int hcur[64];
    __shared__ int smax[32];
    __shared__ int sbase[33];
    __shared__ int is32;
    const int tid = threadIdx.x;
    cnt[tid] = 0;
    if (tid < 64) { hist[tid] = 0; hcur[tid] = 0; }
    if (tid == 0) is32 = 0;
    __syncthreads();
    int f = 0;
    for (int idx = tid * 2 + 1; idx < nnz * 4; idx += 512) f |= wi[idx];
    if (f) atomicOr(&is32, 1);
    __syncthreads();
    const int stride = is32 ? 4 : 8;
    const int step   = is32 ? 1 : 2;
    for (int e = tid; e < nnz; e += 256)
        atomicAdd(&cnt[wi[e * stride]], 1);
    __syncthreads();
    { int key = 63 - min(cnt[tid], 63); atomicAdd(&hist[key], 1); }
    __syncthreads();
    if (tid == 0) {
        int s = 0;
        for (int i = 0; i < 64; ++i) { hbase[i] = s; s += hist[i]; }
        hbase[64] = s;
    }
    __syncthreads();
    { int key = 63 - min(cnt[tid], 63);
      int pos = hbase[key] + atomicAdd(&hcur[key], 1);
      ipos[tid] = pos; prm[pos] = tid; }
    __syncthreads();
    if (tid < 32) {
        int m = 0;
        for (int k = 0; k < 8; ++k) m = max(m, cnt[prm[tid * 8 + k]]);
        smax[tid] = m;
    }
    __syncthreads();
    if (tid == 0) {
        int s = 0;
        for (int i = 0; i < 32; ++i) { sbase[i] = s; s += 8 * smax[i]; }
        sbase[32] = s;
    }
    __syncthreads();
    const int T = sbase[32];
    for (int i = tid; i < T; i += 256) tab[i] = make_int2(0, 0);
    cnt[tid] = 0;
    __syncthreads();
    for (int e = tid; e < nnz; e += 256) {
        int o  = wi[e * stride];
        int h  = wi[e * stride + 1 * step];
        int w_ = wi[e * stride + 2 * step];
        int c  = wi[e * stride + 3 * step];
        int k   = h * 768 + w_ * 256 + c;
        int cp  = k / 9;
        int rem = k - cp * 9;
        int i_  = rem / 3;
        int j_  = rem - i_ * 3;
        int meta2 = i_ * ROWB + j_ * COLB + cp * 2;
        int slot = atomicAdd(&cnt[o], 1);
        int p    = ipos[o];
        tab[sbase[p >> 3] + slot * 8 + (p & 7)] = make_int2(meta2, __float_as_int(wv[e]));
    }
    if (tid < 32) sgS[tid] = smax[tid];
    if (tid < 33) sgBase[tid] = sbase[tid];
    perm[tid] = prm[tid];
}

// round-to-nearest-even fp32 -> bf16 bits
__device__ inline unsigned short rtne_bf16(float f) {
    unsigned u = __float_as_uint(f);
    u += 0x7FFFu + ((u >> 16) & 1u);
    return (unsigned short)(u >> 16);
}

__device__ __forceinline__ float bfld(const char* b, int off) {
    return __uint_as_float(((unsigned)*(const unsigned short*)(b + off)) << 16);
}

// ---------------- main conv kernel ----------------
// Round 6 structure (best measured: 44.5us) + two conflict fixes:
//   stage: lane-permuted channel assignment -> 2-way (free) write banks
//   flush: SST=17 odd stride -> conflict-free scalar stores
__global__ __launch_bounds__(1024, 8)
void conv_kernel(const float* __restrict__ in, float* __restrict__ out,
                 const int* __restrict__ sgS, const int* __restrict__ sgBase,
                 const int* __restrict__ perm, const int2* __restrict__ tab) {
    extern __shared__ char smem[];
    float* ldsF = (float*)smem;

    const int tid  = threadIdx.x;
    const int w    = __builtin_amdgcn_readfirstlane(tid >> 6);  // wave id 0..15 in SGPR
    const int lane = tid & 63;
    const int tx = blockIdx.x, ty = blockIdx.y, b = blockIdx.z;
    const int iy0 = ty * TY, ix0 = tx * TX;
    const float* inb = in + (size_t)b * (H_IN * W_IN * C_IN);

    // ---- stage input tile: 100 px x 256 ch fp32 -> bf16 in LDS ----
    // pl: bijective lane permutation (XOR bits 4-5 into 2-3). Lane pl(l) loads
    // channels 4*pl..4*pl+3 (same coalesced 1KB segment) and writes them at
    // halfword 4*pl: write bank 2*pl mod 32 = exactly 2 lanes/bank (free).
    // Channel c still lands at offset c -> gather untouched.
    const int pl = lane ^ ((lane >> 4) << 2);
    for (int base = 0; base < 8; base += 4) {
        float4 v[4];
#pragma unroll
        for (int q = 0; q < 4; ++q) {
            int p = w + (base + q) * NWAVES;
            if (p < NPIX) {
                int r = p / ICOLS, c = p - r * ICOLS;
                int gy = iy0 + r, gx = ix0 + c;
                if (gy < H_IN && gx < W_IN)   // wave-uniform
                    v[q] = *(const float4*)(inb + ((gy * W_IN + gx) << 8) + (pl << 2));
            }
        }
#pragma unroll
        for (int q = 0; q < 4; ++q) {
            int p = w + (base + q) * NWAVES;
            if (p < NPIX) {
                int r = p / ICOLS, c = p - r * ICOLS;
                int gy = iy0 + r, gx = ix0 + c;
                if (gy < H_IN && gx < W_IN) {
                    ushort2 lo, hi;
                    lo.x = rtne_bf16(v[q].x); lo.y = rtne_bf16(v[q].y);
                    hi.x = rtne_bf16(v[q].z); hi.y = rtne_bf16(v[q].w);
                    unsigned short* d = (unsigned short*)(smem + r * ROWB + c * COLB) + (pl << 2);
                    *(ushort2*)(d)     = lo;
                    *(ushort2*)(d + 2) = hi;
                }
            }
        }
    }
    __syncthreads();

    // ---- gather: lane = output pixel (8x8); wave owns sorted groups {w, 31-w} ----
    const int A2  = (lane >> 3) * ROWB + (lane & 7) * COLB;   // byte base of lane's pixel
    const int g0 = w, g1 = 31 - w;
    const char* basep = (const char*)smem;
    float acc[OPW];
#pragma unroll
    for (int i = 0; i < OPW; ++i) acc[i] = 0.f;

#pragma unroll
    for (int g = 0; g < 2; ++g) {
        const int gi = g ? g1 : g0;
        const int S = sgS[gi];
        const int2* Tg = tab + sgBase[gi];
        for (int slot = 0; slot < S; ++slot) {
            const int4* R = (const int4*)(Tg + (slot << 3));   // 64 B, wave-uniform, cache-hot
            const int4 p0 = R[0];
            const int4 p1 = R[1];
            const int4 p2 = R[2];
            const int4 p3 = R[3];
            acc[g * 8 + 0] += __int_as_float(p0.y) * bfld(basep, A2 + p0.x);
            acc[g * 8 + 1] += __int_as_float(p0.w) * bfld(basep, A2 + p0.z);
            acc[g * 8 + 2] += __int_as_float(p1.y) * bfld(basep, A2 + p1.x);
            acc[g * 8 + 3] += __int_as_float(p1.w) * bfld(basep, A2 + p1.z);
            acc[g * 8 + 4] += __int_as_float(p2.y) * bfld(basep, A2 + p2.x);
            acc[g * 8 + 5] += __int_as_float(p2.w) * bfld(basep, A2 + p2.z);
            acc[g * 8 + 6] += __int_as_float(p3.y) * bfld(basep, A2 + p3.x);
            acc[g * 8 + 7] += __int_as_float(p3.w) * bfld(basep, A2 + p3.z);
        }
    }

    // ---- flush: route acc -> true channels through the LDS transpose stage ----
    __syncthreads();                                   // (B1) input region dead
    int tcs[OPW];
#pragma unroll
    for (int k = 0; k < OPW; ++k) {
        const int grp = (k < 8) ? g0 : g1;
        tcs[k] = perm[grp * 8 + (k & 7)];              // true output channel of acc[k]
    }
    const int ob = w * OPW;
    // pass 0: stage true channels [0,128) (all waves write their subset)
#pragma unroll
    for (int k = 0; k < OPW; ++k) {
        const int tc = tcs[k];
        if ((tc >> 7) == 0)
            ldsF[((tc >> 4) & 7) * STG_W + lane * SST + (tc & 15)] = acc[k];
    }
    __syncthreads();                                   // (B2)
    if (w < 8) {
        const int a_  = lane >> 2;     // pixel sub-index 0..15
        const int chq = lane & 3;      // channel quad 0..3
        const float* rb = ldsF + w * STG_W;
#pragma unroll
        for (int s16 = 0; s16 < 4; ++s16) {
            int p = s16 * 16 + a_;
            const float* rp = rb + p * SST + chq * 4;  // odd stride: scalar b32 reads
            float u0 = rp[0], u1 = rp[1], u2 = rp[2], u3 = rp[3];
            int poy = iy0 + (p >> 3), pox = ix0 + (p & 7);
            if (poy < OH && pox < OW) {
                float4 o4 = make_float4(u0, u1, u2, u3);
                *(float4*)(out + (((size_t)b * OH + poy) * OW + pox) * O_OUT + ob + chq * 4) = o4;
            }
        }
    }
    __syncthreads();                                   // (B3) pass-0 reads done
    // pass 1: stage true channels [128,256)
#pragma unroll
    for (int k = 0; k < OPW; ++k) {
        const int tc = tcs[k];
        if ((tc >> 7) == 1)
            ldsF[((tc >> 4) & 7) * STG_W + lane * SST + (tc & 15)] = acc[k];
    }
    __syncthreads();                                   // (B4)
    if (w >= 8) {
        const int a_  = lane >> 2;
        const int chq = lane & 3;
        const float* rb = ldsF + (w & 7) * STG_W;
#pragma unroll
        for (int s16 = 0; s16 < 4; ++s16) {
            int p = s16 * 16 + a_;
            const float* rp = rb + p * SST + chq * 4;
            float u0 = rp[0], u1 = rp[1], u2 = rp[2], u3 = rp[3];
            int poy = iy0 + (p >> 3), pox = ix0 + (p & 7);
            if (poy < OH && pox < OW) {
                float4 o4 = make_float4(u0, u1, u2, u3);
                *(float4*)(out + (((size_t)b * OH + poy) * OW + pox) * O_OUT + ob + chq * 4) = o4;
            }
        }
    }
}

// ---------------- host ----------------
extern "C" void kernel_launch(void* const* d_in, const int* in_sizes, int n_in,
                              void* d_out, int out_size, void* d_ws, size_t ws_size,
                              hipStream_t stream) {
    const float* input = (const float*)d_in[0];
    const int*   widx  = (const int*)d_in[1];    // int32 or int64 (runtime-detected)
    const float* wval  = (const float*)d_in[2];
    float* outp = (float*)d_out;
    const int nnz = in_sizes[2];
    const int B = in_sizes[0] / (H_IN * W_IN * C_IN);

    int*  sgS    = (int*)d_ws;                       // 32 ints
    int*  sgBase = sgS + 32;                         // 33 ints
    int*  perm   = (int*)((char*)d_ws + 512);        // 256 ints
    int2* tab    = (int2*)((char*)d_ws + 2048);      // worst case 8*nnz entries

    prep_kernel<<<1, 256, 0, stream>>>(widx, wval, nnz, sgS, sgBase, perm, tab);

    static_assert(LDS_BYTES >= FLUSH_BYTES, "flush pass must fit in input region");
    static_assert(2 * LDS_BYTES <= 160 * 1024, "2 blocks/CU");
    hipFuncSetAttribute((const void*)conv_kernel,
                        hipFuncAttributeMaxDynamicSharedMemorySize, LDS_BYTES);
    dim3 grid((OW + TX - 1) / TX, (OH + TY - 1) / TY, B);
    conv_kernel<<<grid, 1024, LDS_BYTES, stream>>>(input, outp, sgS, sgBase, perm, tab);
}